// Round 2
// baseline (358.011 us; speedup 1.0000x reference)
//
#include <hip/hip_runtime.h>
#include <math.h>

#define B 16
#define NAV 36
#define HIM 120
#define WIM 160
#define RH 512
#define NF 4
#define AE 37

// ---------------- workspace layout (floats) ----------------
// attn   : [B*NAV]            @ 0        (576)
// dfa    : [B*NF]             @ 576      (64)
// vf_raw : [2][B][3][12]      @ 640      (1152)
// y1     : [2][B][64][269]    @ 1792     (550912)
// pano   : [B][360][1920]     @ 552704   (11059200)

// ============ kernel 1: attn softmax + dynamic-filter MLP ============
__global__ __launch_bounds__(128) void k_head(
    const float* __restrict__ nnf, const float* __restrict__ ctx,
    const float* __restrict__ fc1w, const float* __restrict__ fc1b,
    const float* __restrict__ fc2w, const float* __restrict__ fc2b,
    float* __restrict__ attn, float* __restrict__ dfa) {
  int b = blockIdx.x;
  int t = threadIdx.x;  // 128 threads
  __shared__ float s_ctx[RH];
  __shared__ float s_v[NAV];
  __shared__ float s_hid[128];
  __shared__ float s_l[NF];
  __shared__ float s_inv[2];

  if (t < NAV) s_v[t] = nnf[b * NAV + t];
  for (int k = t; k < RH; k += 128) s_ctx[k] = ctx[b * RH + k];
  __syncthreads();

  if (t == 0) {
    float m = -1e30f;
    for (int i = 0; i < NAV; i++) m = fmaxf(m, s_v[i]);
    float s = 0.f;
    for (int i = 0; i < NAV; i++) { s_v[i] = expf(s_v[i] - m); s += s_v[i]; }
    s_inv[0] = 1.0f / s;
  }
  float acc = fc1b[t];
  const float* wr = fc1w + t * RH;
  for (int k = 0; k < RH; k++) acc += s_ctx[k] * wr[k];
  s_hid[t] = fmaxf(acc, 0.0f);
  __syncthreads();

  if (t < NAV) attn[b * NAV + t] = s_v[t] * s_inv[0];
  if (t < NF) {
    float a = fc2b[t];
    const float* w2 = fc2w + t * 128;
    for (int k = 0; k < 128; k++) a += s_hid[k] * w2[k];
    s_l[t] = a;
  }
  __syncthreads();
  if (t == 0) {
    float m = fmaxf(fmaxf(s_l[0], s_l[1]), fmaxf(s_l[2], s_l[3]));
    float s = 0.f;
    for (int f = 0; f < NF; f++) { s_l[f] = expf(s_l[f] - m); s += s_l[f]; }
    s_inv[1] = 1.0f / s;
  }
  __syncthreads();
  if (t < NF) dfa[b * NF + t] = s_l[t] * s_inv[1];
}

// ============ kernel 2: fused conv1 + attn-scale + dynamic conv -> pano ============
// tile: TH=8 output rows x full width (160) of one (b, group i) plane.
// Vectorized: threads compute 4 consecutive x outputs via register sliding
// window; all LDS reads are aligned b128 (row strides 168/164 floats = 16B mult).
#define TH 8
__global__ __launch_bounds__(256) void k_conv(
    const float* __restrict__ draw, const float* __restrict__ dclip,
    const float* __restrict__ obj,
    const float* __restrict__ c1w, const float* __restrict__ c1b,
    const float* __restrict__ dynf,
    const float* __restrict__ attn, const float* __restrict__ dfa,
    float* __restrict__ pano) {
  __shared__ float s_raw[16][168];   // rows y0-4..y0+11, col j = gx+4 (gx -4..163)
  __shared__ float s_clip[16][168];
  __shared__ float s_pd[12][164];    // rows y0-2..y0+9, col i = c+2 (c -2..161)
  __shared__ float s_obj[12][164];   // attn*obj, same indexing as s_pd
  __shared__ float s_w1[50];
  __shared__ float s_k[50];

  int t = threadIdx.x;
  int bz = blockIdx.z;
  int b = bz / NAV, i = bz % NAV;
  int y0 = blockIdx.y * TH;
  const size_t plane = (size_t)(b * NAV + i) * HIM * WIM;
  const float* rawp = draw + plane;
  const float* clipp = dclip + plane;
  const float* objp = obj + plane;
  float attn_bi = attn[b * NAV + i];

  if (t < 50) {
    s_w1[t] = c1w[i * 50 + t];
  } else if (t >= 64 && t < 114) {
    int j = t - 64;
    float a = 0.f;
    for (int f = 0; f < NF; f++) a += dfa[b * NF + f] * dynf[(f * NAV + i) * 50 + j];
    s_k[j] = a;
  }

  // stage raw/clip: 16 rows x 42 float4 groups (group g covers gx = 4g-4..4g-1)
  for (int tt = t; tt < 672; tt += 256) {
    int rr = tt / 42, g = tt % 42;
    int gy = y0 - 4 + rr;
    float4 vr = {0.f, 0.f, 0.f, 0.f}, vc = {0.f, 0.f, 0.f, 0.f};
    if (gy >= 0 && gy < HIM && g >= 1 && g <= 40) {
      int gx = 4 * g - 4;
      vr = *(const float4*)&rawp[gy * WIM + gx];
      vc = *(const float4*)&clipp[gy * WIM + gx];
    }
    *(float4*)&s_raw[rr][4 * g] = vr;
    *(float4*)&s_clip[rr][4 * g] = vc;
  }
  // stage attn*obj: 12 rows x 82 float2 groups (group h covers gx = 2h-2..2h-1)
  for (int tt = t; tt < 984; tt += 256) {
    int r = tt / 82, h = tt % 82;
    int gy = y0 - 2 + r;
    float2 v = {0.f, 0.f};
    if (gy >= 0 && gy < HIM && h >= 1 && h <= 80) {
      int gx = 2 * h - 2;
      v = *(const float2*)&objp[gy * WIM + gx];
      v.x *= attn_bi; v.y *= attn_bi;
    }
    *(float2*)&s_obj[r][2 * h] = v;
  }
  __syncthreads();

  // preload conv1 weights to registers (broadcast reads, once per thread)
  float wreg[50];
#pragma unroll
  for (int k = 0; k < 50; k++) wreg[k] = s_w1[k];

  float bias = c1b[i];
  // pd stage: 12 rows x 41 groups of 4 (pd idx i0..i0+3; raw window j = i0..i0+7)
  for (int tt = t; tt < 492; tt += 256) {
    int r = tt / 41, g = tt % 41;
    int i0 = 4 * g;
    int y = y0 - 2 + r;
    float a0 = bias, a1 = bias, a2 = bias, a3 = bias;
    if (y >= 0 && y < HIM) {
#pragma unroll
      for (int ky = 0; ky < 5; ky++) {
        const float* rw = &s_raw[r + ky][i0];
        const float* cl = &s_clip[r + ky][i0];
        float v[8], u[8];
        *(float4*)&v[0] = *(const float4*)rw;
        *(float4*)&v[4] = *(const float4*)(rw + 4);
        *(float4*)&u[0] = *(const float4*)cl;
        *(float4*)&u[4] = *(const float4*)(cl + 4);
#pragma unroll
        for (int kx = 0; kx < 5; kx++) {
          float w0 = wreg[ky * 5 + kx], w1 = wreg[25 + ky * 5 + kx];
          a0 += v[kx] * w0 + u[kx] * w1;
          a1 += v[kx + 1] * w0 + u[kx + 1] * w1;
          a2 += v[kx + 2] * w0 + u[kx + 2] * w1;
          a3 += v[kx + 3] * w0 + u[kx + 3] * w1;
        }
      }
    }
    bool yok = (y >= 0 && y < HIM);
    float4 o4;
    o4.x = (yok && (i0 + 0 >= 2) && (i0 + 0 < 162)) ? a0 * attn_bi : 0.f;
    o4.y = (yok && (i0 + 1 >= 2) && (i0 + 1 < 162)) ? a1 * attn_bi : 0.f;
    o4.z = (yok && (i0 + 2 >= 2) && (i0 + 2 < 162)) ? a2 * attn_bi : 0.f;
    o4.w = (yok && (i0 + 3 >= 2) && (i0 + 3 < 162)) ? a3 * attn_bi : 0.f;
    *(float4*)&s_pd[r][i0] = o4;
  }
  __syncthreads();

  // preload dyn weights to registers
  float kreg[50];
#pragma unroll
  for (int k = 0; k < 50; k++) kreg[k] = s_k[k];

  int q = i / 12, cw = i % 12;
  float* outp = pano + (size_t)b * 360 * 1920 + (size_t)((2 - q) * HIM) * 1920 + cw * WIM;
  // out stage: 8 rows x 40 groups of 4 (window idx = x0..x0+7 in s_pd/s_obj)
  for (int tt = t; tt < 320; tt += 256) {
    int dy = tt / 40, g = tt % 40;
    int x0 = 4 * g;
    float a0 = 0.f, a1 = 0.f, a2 = 0.f, a3 = 0.f;
#pragma unroll
    for (int ky = 0; ky < 5; ky++) {
      const float* pr = &s_pd[dy + ky][x0];
      const float* ob = &s_obj[dy + ky][x0];
      float p[8], o[8];
      *(float4*)&p[0] = *(const float4*)pr;
      *(float4*)&p[4] = *(const float4*)(pr + 4);
      *(float4*)&o[0] = *(const float4*)ob;
      *(float4*)&o[4] = *(const float4*)(ob + 4);
#pragma unroll
      for (int kx = 0; kx < 5; kx++) {
        float k1 = kreg[ky * 5 + kx], k2 = kreg[25 + ky * 5 + kx];
        a0 += p[kx] * k1 + o[kx] * k2;
        a1 += p[kx + 1] * k1 + o[kx + 1] * k2;
        a2 += p[kx + 2] * k1 + o[kx + 2] * k2;
        a3 += p[kx + 3] * k1 + o[kx + 3] * k2;
      }
    }
    float4 o4 = {a0, a1, a2, a3};
    *(float4*)&outp[(size_t)(y0 + dy) * 1920 + x0] = o4;
  }
}

// ============ kernel 3: conv2_1, both roll paths, LDS row staging ============
// block = (b, oy); stages the 5 pano rows used (stride-10 dilation), computes
// 2*269 outputs from LDS (stride-7 reads: gcd(7,32)=1 -> conflict-free).
__global__ __launch_bounds__(256) void k_c21(
    const float* __restrict__ pano, const float* __restrict__ w21,
    const float* __restrict__ b21, float* __restrict__ y1) {
  __shared__ float s_rows[5][1920];
  int t = threadIdx.x;
  int b = blockIdx.x, oy = blockIdx.y;
  const float* pp = pano + (size_t)b * 691200;
  for (int tt = t; tt < 2400; tt += 256) {
    int ky = tt / 480, g = tt % 480;
    int row = 5 * oy + 10 * ky;
    *(float4*)&s_rows[ky][4 * g] = *(const float4*)&pp[(size_t)row * 1920 + 4 * g];
  }
  float w[25];
#pragma unroll
  for (int k = 0; k < 25; k++) w[k] = w21[k];
  float bb = b21[0];
  __syncthreads();
  for (int tt = t; tt < 538; tt += 256) {
    int p = tt / 269, ox = tt % 269;
    int shift = p ? 1760 : 0;  // roll by +160 cols
    float acc = bb;
#pragma unroll
    for (int ky = 0; ky < 5; ky++)
#pragma unroll
      for (int kx = 0; kx < 5; kx++) {
        int X = 7 * ox + 10 * kx + shift;
        if (X >= 1920) X -= 1920;
        acc += w[ky * 5 + kx] * s_rows[ky][X];
      }
    y1[((size_t)(p * B + b) * 64 + oy) * 269 + ox] = acc;
  }
}

// ============ kernel 4: avgpool(3,3)/3 -> conv2_2 -> avgpool(3,9)/3 ============
__global__ __launch_bounds__(256) void k_tail(
    const float* __restrict__ y1, const float* __restrict__ w22,
    const float* __restrict__ b22, float* __restrict__ vf_raw) {
  __shared__ float s_y2[21][90];
  __shared__ float s_y3[10][44];
  int t = threadIdx.x;
  int pb = blockIdx.x;  // p*B+b
  const float* yp = y1 + (size_t)pb * 64 * 269;
  for (int idx = t; idx < 21 * 89; idx += 256) {
    int py = idx / 89, px = idx % 89;
    float s = 0.f;
    for (int dy = 0; dy < 3; dy++)
      for (int dx = 0; dx < 3; dx++)
        s += yp[(3 * py + dy) * 269 + 3 * px + dx];
    s_y2[py][px] = s * (1.0f / 9.0f);
  }
  __syncthreads();
  for (int idx = t; idx < 10 * 43; idx += 256) {
    int qy = idx / 43, qx = idx % 43;
    float a = b22[0];
#pragma unroll
    for (int ky = 0; ky < 3; ky++)
#pragma unroll
      for (int kx = 0; kx < 3; kx++)
        a += w22[ky * 3 + kx] * s_y2[2 * qy + ky][2 * qx + 2 * kx];
    s_y3[qy][qx] = a;
  }
  __syncthreads();
  if (t < 36) {
    int uy = t / 12, ux = t % 12;
    float s = 0.f;
    for (int dy = 0; dy < 3; dy++)
      for (int dx = 0; dx < 9; dx++)
        s += s_y3[3 * uy + dy][3 * ux + dx];
    vf_raw[pb * 36 + t] = s * (1.0f / 27.0f);
  }
}

// ============ kernel 5: combine paths, flip, softmax(T=10), nav_mask ============
__global__ __launch_bounds__(64) void k_vf(
    const float* __restrict__ vf_raw, const int* __restrict__ nav_idx,
    float* __restrict__ out_vf, float* __restrict__ out_mask) {
  int b = blockIdx.x;
  int t = threadIdx.x;  // 64
  __shared__ float s_v[36];
  __shared__ float s_inv;
  if (t < 36) {
    int u = t / 12, x = t % 12;
    float v1 = vf_raw[(0 * B + b) * 36 + (2 - u) * 12 + x];
    float v2 = vf_raw[(1 * B + b) * 36 + (2 - u) * 12 + (x + 1) % 12];
    s_v[t] = 0.5f * (v1 + v2) * 0.1f;  // /TEMP
  }
  __syncthreads();
  if (t == 0) {
    float m = -1e30f;
    for (int i = 0; i < 36; i++) m = fmaxf(m, s_v[i]);
    float s = 0.f;
    for (int i = 0; i < 36; i++) { s_v[i] = expf(s_v[i] - m); s += s_v[i]; }
    s_inv = 1.0f / s;
  }
  __syncthreads();
  if (t < 36) {
    out_vf[b * 36 + t] = s_v[t] * s_inv;
    float m = 0.f;
    for (int e = 0; e < 8; e++)
      if (nav_idx[b * 8 + e] == t) m = 1.0f;
    out_mask[b * 36 + t] = m;
  }
}

// ============ kernel 6: LSTM cell ============
__global__ __launch_bounds__(256) void k_lstm(
    const float* __restrict__ ctx, const float* __restrict__ vf,
    const float* __restrict__ dfa, const float* __restrict__ pre,
    const float* __restrict__ h0, const float* __restrict__ c0,
    const float* __restrict__ wih, const float* __restrict__ whh,
    const float* __restrict__ bih, const float* __restrict__ bhh,
    float* __restrict__ h1, float* __restrict__ c1) {
  __shared__ float s_cat[B][593];
  __shared__ float s_g[32][16];
  int t = threadIdx.x;
  int u0 = blockIdx.x * 8;
  for (int idx = t; idx < B * 589; idx += 256) {
    int b = idx / 589, k = idx % 589;
    float v;
    if (k < 512) v = ctx[b * 512 + k];
    else if (k < 548) v = vf[b * 36 + (k - 512)];
    else if (k < 552) v = dfa[b * 4 + (k - 548)];
    else v = pre[b * 37 + (k - 552)];
    s_cat[b][k] = v;
  }
  __syncthreads();
  int b = t & 15;
  int s0 = t >> 4;
  for (int rep = 0; rep < 2; rep++) {
    int slot = s0 + rep * 16;
    int gate = slot >> 3, du = slot & 7;
    int j = gate * 512 + u0 + du;
    float acc = bih[j] + bhh[j];
    const float* wi = wih + (size_t)j * 589;
    for (int k = 0; k < 589; k++) acc += s_cat[b][k] * wi[k];
    const float* wh = whh + (size_t)j * 512;
    const float* hb = h0 + b * 512;
    for (int k = 0; k < 512; k++) acc += hb[k] * wh[k];
    s_g[slot][b] = acc;
  }
  __syncthreads();
  if (t < 128) {
    int bb = t & 15, du = t >> 4;
    float gi = s_g[0 + du][bb], gf = s_g[8 + du][bb];
    float gg = s_g[16 + du][bb], go = s_g[24 + du][bb];
    int u = u0 + du;
    float c_old = c0[bb * 512 + u];
    float si = 1.0f / (1.0f + expf(-gi));
    float sf = 1.0f / (1.0f + expf(-gf));
    float so = 1.0f / (1.0f + expf(-go));
    float cn = sf * c_old + si * tanhf(gg);
    h1[bb * 512 + u] = so * tanhf(cn);
    c1[bb * 512 + u] = cn;
  }
}

extern "C" void kernel_launch(void* const* d_in, const int* in_sizes, int n_in,
                              void* d_out, int out_size, void* d_ws, size_t ws_size,
                              hipStream_t stream) {
  const float* depth_raw  = (const float*)d_in[0];
  const float* depth_clip = (const float*)d_in[1];
  const float* obj_feat   = (const float*)d_in[2];
  const float* nnf        = (const float*)d_in[3];
  const float* pre        = (const float*)d_in[4];
  const float* h0         = (const float*)d_in[5];
  const float* c0         = (const float*)d_in[6];
  const float* ctx        = (const float*)d_in[7];
  const int*   nav_idx    = (const int*)d_in[8];
  const float* c1w        = (const float*)d_in[9];
  const float* c1b        = (const float*)d_in[10];
  const float* fc1w       = (const float*)d_in[11];
  const float* fc1b       = (const float*)d_in[12];
  const float* fc2w       = (const float*)d_in[13];
  const float* fc2b       = (const float*)d_in[14];
  const float* dynf       = (const float*)d_in[15];
  const float* w21        = (const float*)d_in[16];
  const float* b21        = (const float*)d_in[17];
  const float* w22        = (const float*)d_in[18];
  const float* b22        = (const float*)d_in[19];
  const float* wih        = (const float*)d_in[20];
  const float* whh        = (const float*)d_in[21];
  const float* bih        = (const float*)d_in[22];
  const float* bhh        = (const float*)d_in[23];

  float* ws = (float*)d_ws;
  float* attn   = ws;
  float* dfa    = ws + 576;
  float* vf_raw = ws + 640;
  float* y1     = ws + 1792;
  float* pano   = ws + 552704;

  float* out = (float*)d_out;
  float* out_h1   = out;
  float* out_c1   = out + 8192;
  float* out_vf   = out + 16384;
  float* out_mask = out + 16960;

  k_head<<<B, 128, 0, stream>>>(nnf, ctx, fc1w, fc1b, fc2w, fc2b, attn, dfa);
  k_conv<<<dim3(1, 15, B * NAV), 256, 0, stream>>>(depth_raw, depth_clip, obj_feat,
                                                   c1w, c1b, dynf, attn, dfa, pano);
  k_c21<<<dim3(B, 64), 256, 0, stream>>>(pano, w21, b21, y1);
  k_tail<<<2 * B, 256, 0, stream>>>(y1, w22, b22, vf_raw);
  k_vf<<<B, 64, 0, stream>>>(vf_raw, nav_idx, out_vf, out_mask);
  k_lstm<<<64, 256, 0, stream>>>(ctx, out_vf, dfa, pre, h0, c0,
                                 wih, whh, bih, bhh, out_h1, out_c1);
}

// Round 3
// 253.105 us; speedup vs baseline: 1.4145x; 1.4145x over previous
//
#include <hip/hip_runtime.h>
#include <math.h>

#define B 16
#define NAV 36
#define HIM 120
#define WIM 160
#define RH 512
#define NF 4
#define AE 37

// ---------------- workspace layout (floats) ----------------
// attn   : [B*NAV]            @ 0        (576)
// dfa    : [B*NF]             @ 576      (64)
// vf_raw : [2][B][3][12]      @ 640      (1152)
// y1     : [2][B][64][269]    @ 1792     (550912)
// pano   : [B][360][1920]     @ 552704   (11059200)

// ============ kernel 1: attn softmax + dynamic-filter MLP ============
__global__ __launch_bounds__(128) void k_head(
    const float* __restrict__ nnf, const float* __restrict__ ctx,
    const float* __restrict__ fc1w, const float* __restrict__ fc1b,
    const float* __restrict__ fc2w, const float* __restrict__ fc2b,
    float* __restrict__ attn, float* __restrict__ dfa) {
  int b = blockIdx.x;
  int t = threadIdx.x;  // 128 threads
  __shared__ float s_ctx[RH];
  __shared__ float s_v[NAV];
  __shared__ float s_hid[128];
  __shared__ float s_l[NF];
  __shared__ float s_inv[2];

  if (t < NAV) s_v[t] = nnf[b * NAV + t];
  for (int k = t; k < RH; k += 128) s_ctx[k] = ctx[b * RH + k];
  __syncthreads();

  if (t == 0) {
    float m = -1e30f;
    for (int i = 0; i < NAV; i++) m = fmaxf(m, s_v[i]);
    float s = 0.f;
    for (int i = 0; i < NAV; i++) { s_v[i] = expf(s_v[i] - m); s += s_v[i]; }
    s_inv[0] = 1.0f / s;
  }
  float acc = fc1b[t];
  const float* wr = fc1w + t * RH;
  for (int k = 0; k < RH; k++) acc += s_ctx[k] * wr[k];
  s_hid[t] = fmaxf(acc, 0.0f);
  __syncthreads();

  if (t < NAV) attn[b * NAV + t] = s_v[t] * s_inv[0];
  if (t < NF) {
    float a = fc2b[t];
    const float* w2 = fc2w + t * 128;
    for (int k = 0; k < 128; k++) a += s_hid[k] * w2[k];
    s_l[t] = a;
  }
  __syncthreads();
  if (t == 0) {
    float m = fmaxf(fmaxf(s_l[0], s_l[1]), fmaxf(s_l[2], s_l[3]));
    float s = 0.f;
    for (int f = 0; f < NF; f++) { s_l[f] = expf(s_l[f] - m); s += s_l[f]; }
    s_inv[1] = 1.0f / s;
  }
  __syncthreads();
  if (t < NF) dfa[b * NF + t] = s_l[t] * s_inv[1];
}

// ============ kernel 2: fused conv1 + attn-scale + dynamic conv -> pano ============
// tile: TH=8 output rows x full width of one (b,i) plane.
// Scalar (stride-1, conflict-free) LDS reads; 4 y-stacked outputs per thread
// reuse each input row across the 5-tap y window (8 rows feed 4 outputs).
// Weights held in a 50-reg array live only within one stage.
#define TH 8
__global__ __launch_bounds__(256) void k_conv(
    const float* __restrict__ draw, const float* __restrict__ dclip,
    const float* __restrict__ obj,
    const float* __restrict__ c1w, const float* __restrict__ c1b,
    const float* __restrict__ dynf,
    const float* __restrict__ attn, const float* __restrict__ dfa,
    float* __restrict__ pano) {
  __shared__ float s_raw[16][168];   // rows y0-4..y0+11, col j = gx+4
  __shared__ float s_clip[16][168];
  __shared__ float s_pd[12][164];    // rows y0-2..y0+9, col i = x+2
  __shared__ float s_obj[12][164];   // attn*obj, same indexing
  __shared__ float s_w1[50];
  __shared__ float s_k[50];

  int t = threadIdx.x;
  int bz = blockIdx.z;
  int b = bz / NAV, i = bz % NAV;
  int y0 = blockIdx.y * TH;
  const size_t plane = (size_t)(b * NAV + i) * HIM * WIM;
  const float* rawp = draw + plane;
  const float* clipp = dclip + plane;
  const float* objp = obj + plane;
  float attn_bi = attn[b * NAV + i];

  if (t < 50) {
    s_w1[t] = c1w[i * 50 + t];
  } else if (t >= 64 && t < 114) {
    int j = t - 64;
    float a = 0.f;
    for (int f = 0; f < NF; f++) a += dfa[b * NF + f] * dynf[(f * NAV + i) * 50 + j];
    s_k[j] = a;
  }
  // stage raw/clip (scalar, proven pattern)
  for (int idx = t; idx < 16 * 168; idx += 256) {
    int rr = idx / 168, cc = idx % 168;
    int gy = y0 - 4 + rr, gx = cc - 4;
    bool ok = (gy >= 0 && gy < HIM && gx >= 0 && gx < WIM);
    s_raw[rr][cc] = ok ? rawp[gy * WIM + gx] : 0.0f;
    s_clip[rr][cc] = ok ? clipp[gy * WIM + gx] : 0.0f;
  }
  __syncthreads();

  // ---- pd stage: 3 row-groups x 164 cols; each thread -> 4 y-stacked pd ----
  {
    float wreg[50];
#pragma unroll
    for (int k = 0; k < 50; k++) wreg[k] = s_w1[k];
    float bias = c1b[i];

    for (int tt = t; tt < 492; tt += 256) {
      int grp = tt / 164, c = tt % 164;
      int base = 4 * grp;           // s_raw row base; pd rows base..base+3
      int x = c - 2;
      float acc0 = bias, acc1 = bias, acc2 = bias, acc3 = bias;
#pragma unroll
      for (int rr = 0; rr < 8; rr++) {
        float v[5], u[5];
#pragma unroll
        for (int kx = 0; kx < 5; kx++) {
          v[kx] = s_raw[base + rr][c + kx];
          u[kx] = s_clip[base + rr][c + kx];
        }
#pragma unroll
        for (int j = 0; j < 4; j++) {
          int ky = rr - j;
          if (ky >= 0 && ky < 5) {
            float a = 0.f;
#pragma unroll
            for (int kx = 0; kx < 5; kx++)
              a += v[kx] * wreg[ky * 5 + kx] + u[kx] * wreg[25 + ky * 5 + kx];
            if (j == 0) acc0 += a;
            else if (j == 1) acc1 += a;
            else if (j == 2) acc2 += a;
            else acc3 += a;
          }
        }
      }
      bool xok = (x >= 0 && x < WIM);
#pragma unroll
      for (int j = 0; j < 4; j++) {
        int r = base + j;
        int y = y0 - 2 + r;
        bool ok = xok && (y >= 0 && y < HIM);
        float av = (j == 0) ? acc0 : (j == 1) ? acc1 : (j == 2) ? acc2 : acc3;
        s_pd[r][c] = ok ? av * attn_bi : 0.0f;
        s_obj[r][c] = ok ? objp[y * WIM + x] * attn_bi : 0.0f;
      }
    }
  }
  __syncthreads();

  // ---- out stage: 2 row-groups x 160 cols; 4 y-stacked outputs ----
  {
    float kreg[50];
#pragma unroll
    for (int k = 0; k < 50; k++) kreg[k] = s_k[k];

    int q = i / 12, cw = i % 12;
    float* outp = pano + (size_t)b * 360 * 1920 +
                  (size_t)((2 - q) * HIM) * 1920 + cw * WIM;
    for (int tt = t; tt < 320; tt += 256) {
      int grp = tt / 160, x = tt % 160;
      int base = 4 * grp;           // s_pd row base; out rows base..base+3
      float acc0 = 0.f, acc1 = 0.f, acc2 = 0.f, acc3 = 0.f;
#pragma unroll
      for (int rr = 0; rr < 8; rr++) {
        float p[5], o[5];
#pragma unroll
        for (int kx = 0; kx < 5; kx++) {
          p[kx] = s_pd[base + rr][x + kx];
          o[kx] = s_obj[base + rr][x + kx];
        }
#pragma unroll
        for (int j = 0; j < 4; j++) {
          int ky = rr - j;
          if (ky >= 0 && ky < 5) {
            float a = 0.f;
#pragma unroll
            for (int kx = 0; kx < 5; kx++)
              a += p[kx] * kreg[ky * 5 + kx] + o[kx] * kreg[25 + ky * 5 + kx];
            if (j == 0) acc0 += a;
            else if (j == 1) acc1 += a;
            else if (j == 2) acc2 += a;
            else acc3 += a;
          }
        }
      }
#pragma unroll
      for (int j = 0; j < 4; j++) {
        float av = (j == 0) ? acc0 : (j == 1) ? acc1 : (j == 2) ? acc2 : acc3;
        outp[(size_t)(y0 + base + j) * 1920 + x] = av;
      }
    }
  }
}

// ============ kernel 3: conv2_1, both roll paths, LDS row staging ============
__global__ __launch_bounds__(256) void k_c21(
    const float* __restrict__ pano, const float* __restrict__ w21,
    const float* __restrict__ b21, float* __restrict__ y1) {
  __shared__ float s_rows[5][1920];
  int t = threadIdx.x;
  int b = blockIdx.x, oy = blockIdx.y;
  const float* pp = pano + (size_t)b * 691200;
  for (int tt = t; tt < 2400; tt += 256) {
    int ky = tt / 480, g = tt % 480;
    int row = 5 * oy + 10 * ky;
    *(float4*)&s_rows[ky][4 * g] = *(const float4*)&pp[(size_t)row * 1920 + 4 * g];
  }
  float w[25];
#pragma unroll
  for (int k = 0; k < 25; k++) w[k] = w21[k];
  float bb = b21[0];
  __syncthreads();
  for (int tt = t; tt < 538; tt += 256) {
    int p = tt / 269, ox = tt % 269;
    int shift = p ? 1760 : 0;  // roll by +160 cols
    float acc = bb;
#pragma unroll
    for (int ky = 0; ky < 5; ky++)
#pragma unroll
      for (int kx = 0; kx < 5; kx++) {
        int X = 7 * ox + 10 * kx + shift;
        if (X >= 1920) X -= 1920;
        acc += w[ky * 5 + kx] * s_rows[ky][X];
      }
    y1[((size_t)(p * B + b) * 64 + oy) * 269 + ox] = acc;
  }
}

// ============ kernel 4: avgpool(3,3)/3 -> conv2_2 -> avgpool(3,9)/3 ============
__global__ __launch_bounds__(256) void k_tail(
    const float* __restrict__ y1, const float* __restrict__ w22,
    const float* __restrict__ b22, float* __restrict__ vf_raw) {
  __shared__ float s_y2[21][90];
  __shared__ float s_y3[10][44];
  int t = threadIdx.x;
  int pb = blockIdx.x;  // p*B+b
  const float* yp = y1 + (size_t)pb * 64 * 269;
  for (int idx = t; idx < 21 * 89; idx += 256) {
    int py = idx / 89, px = idx % 89;
    float s = 0.f;
    for (int dy = 0; dy < 3; dy++)
      for (int dx = 0; dx < 3; dx++)
        s += yp[(3 * py + dy) * 269 + 3 * px + dx];
    s_y2[py][px] = s * (1.0f / 9.0f);
  }
  __syncthreads();
  for (int idx = t; idx < 10 * 43; idx += 256) {
    int qy = idx / 43, qx = idx % 43;
    float a = b22[0];
#pragma unroll
    for (int ky = 0; ky < 3; ky++)
#pragma unroll
      for (int kx = 0; kx < 3; kx++)
        a += w22[ky * 3 + kx] * s_y2[2 * qy + ky][2 * qx + 2 * kx];
    s_y3[qy][qx] = a;
  }
  __syncthreads();
  if (t < 36) {
    int uy = t / 12, ux = t % 12;
    float s = 0.f;
    for (int dy = 0; dy < 3; dy++)
      for (int dx = 0; dx < 9; dx++)
        s += s_y3[3 * uy + dy][3 * ux + dx];
    vf_raw[pb * 36 + t] = s * (1.0f / 27.0f);
  }
}

// ============ kernel 5: combine paths, flip, softmax(T=10), nav_mask ============
__global__ __launch_bounds__(64) void k_vf(
    const float* __restrict__ vf_raw, const int* __restrict__ nav_idx,
    float* __restrict__ out_vf, float* __restrict__ out_mask) {
  int b = blockIdx.x;
  int t = threadIdx.x;  // 64
  __shared__ float s_v[36];
  __shared__ float s_inv;
  if (t < 36) {
    int u = t / 12, x = t % 12;
    float v1 = vf_raw[(0 * B + b) * 36 + (2 - u) * 12 + x];
    float v2 = vf_raw[(1 * B + b) * 36 + (2 - u) * 12 + (x + 1) % 12];
    s_v[t] = 0.5f * (v1 + v2) * 0.1f;  // /TEMP
  }
  __syncthreads();
  if (t == 0) {
    float m = -1e30f;
    for (int i = 0; i < 36; i++) m = fmaxf(m, s_v[i]);
    float s = 0.f;
    for (int i = 0; i < 36; i++) { s_v[i] = expf(s_v[i] - m); s += s_v[i]; }
    s_inv = 1.0f / s;
  }
  __syncthreads();
  if (t < 36) {
    out_vf[b * 36 + t] = s_v[t] * s_inv;
    float m = 0.f;
    for (int e = 0; e < 8; e++)
      if (nav_idx[b * 8 + e] == t) m = 1.0f;
    out_mask[b * 36 + t] = m;
  }
}

// ============ kernel 6: LSTM cell ============
__global__ __launch_bounds__(256) void k_lstm(
    const float* __restrict__ ctx, const float* __restrict__ vf,
    const float* __restrict__ dfa, const float* __restrict__ pre,
    const float* __restrict__ h0, const float* __restrict__ c0,
    const float* __restrict__ wih, const float* __restrict__ whh,
    const float* __restrict__ bih, const float* __restrict__ bhh,
    float* __restrict__ h1, float* __restrict__ c1) {
  __shared__ float s_cat[B][593];
  __shared__ float s_g[32][16];
  int t = threadIdx.x;
  int u0 = blockIdx.x * 8;
  for (int idx = t; idx < B * 589; idx += 256) {
    int b = idx / 589, k = idx % 589;
    float v;
    if (k < 512) v = ctx[b * 512 + k];
    else if (k < 548) v = vf[b * 36 + (k - 512)];
    else if (k < 552) v = dfa[b * 4 + (k - 548)];
    else v = pre[b * 37 + (k - 552)];
    s_cat[b][k] = v;
  }
  __syncthreads();
  int b = t & 15;
  int s0 = t >> 4;
  for (int rep = 0; rep < 2; rep++) {
    int slot = s0 + rep * 16;
    int gate = slot >> 3, du = slot & 7;
    int j = gate * 512 + u0 + du;
    float acc = bih[j] + bhh[j];
    const float* wi = wih + (size_t)j * 589;
    for (int k = 0; k < 589; k++) acc += s_cat[b][k] * wi[k];
    const float* wh = whh + (size_t)j * 512;
    const float* hb = h0 + b * 512;
    for (int k = 0; k < 512; k++) acc += hb[k] * wh[k];
    s_g[slot][b] = acc;
  }
  __syncthreads();
  if (t < 128) {
    int bb = t & 15, du = t >> 4;
    float gi = s_g[0 + du][bb], gf = s_g[8 + du][bb];
    float gg = s_g[16 + du][bb], go = s_g[24 + du][bb];
    int u = u0 + du;
    float c_old = c0[bb * 512 + u];
    float si = 1.0f / (1.0f + expf(-gi));
    float sf = 1.0f / (1.0f + expf(-gf));
    float so = 1.0f / (1.0f + expf(-go));
    float cn = sf * c_old + si * tanhf(gg);
    h1[bb * 512 + u] = so * tanhf(cn);
    c1[bb * 512 + u] = cn;
  }
}

extern "C" void kernel_launch(void* const* d_in, const int* in_sizes, int n_in,
                              void* d_out, int out_size, void* d_ws, size_t ws_size,
                              hipStream_t stream) {
  const float* depth_raw  = (const float*)d_in[0];
  const float* depth_clip = (const float*)d_in[1];
  const float* obj_feat   = (const float*)d_in[2];
  const float* nnf        = (const float*)d_in[3];
  const float* pre        = (const float*)d_in[4];
  const float* h0         = (const float*)d_in[5];
  const float* c0         = (const float*)d_in[6];
  const float* ctx        = (const float*)d_in[7];
  const int*   nav_idx    = (const int*)d_in[8];
  const float* c1w        = (const float*)d_in[9];
  const float* c1b        = (const float*)d_in[10];
  const float* fc1w       = (const float*)d_in[11];
  const float* fc1b       = (const float*)d_in[12];
  const float* fc2w       = (const float*)d_in[13];
  const float* fc2b       = (const float*)d_in[14];
  const float* dynf       = (const float*)d_in[15];
  const float* w21        = (const float*)d_in[16];
  const float* b21        = (const float*)d_in[17];
  const float* w22        = (const float*)d_in[18];
  const float* b22        = (const float*)d_in[19];
  const float* wih        = (const float*)d_in[20];
  const float* whh        = (const float*)d_in[21];
  const float* bih        = (const float*)d_in[22];
  const float* bhh        = (const float*)d_in[23];

  float* ws = (float*)d_ws;
  float* attn   = ws;
  float* dfa    = ws + 576;
  float* vf_raw = ws + 640;
  float* y1     = ws + 1792;
  float* pano   = ws + 552704;

  float* out = (float*)d_out;
  float* out_h1   = out;
  float* out_c1   = out + 8192;
  float* out_vf   = out + 16384;
  float* out_mask = out + 16960;

  k_head<<<B, 128, 0, stream>>>(nnf, ctx, fc1w, fc1b, fc2w, fc2b, attn, dfa);
  k_conv<<<dim3(1, 15, B * NAV), 256, 0, stream>>>(depth_raw, depth_clip, obj_feat,
                                                   c1w, c1b, dynf, attn, dfa, pano);
  k_c21<<<dim3(B, 64), 256, 0, stream>>>(pano, w21, b21, y1);
  k_tail<<<2 * B, 256, 0, stream>>>(y1, w22, b22, vf_raw);
  k_vf<<<B, 64, 0, stream>>>(vf_raw, nav_idx, out_vf, out_mask);
  k_lstm<<<64, 256, 0, stream>>>(ctx, out_vf, dfa, pre, h0, c0,
                                 wih, whh, bih, bhh, out_h1, out_c1);
}

// Round 4
// 225.402 us; speedup vs baseline: 1.5883x; 1.1229x over previous
//
#include <hip/hip_runtime.h>
#include <math.h>

#define B 16
#define NAV 36
#define HIM 120
#define WIM 160
#define RH 512
#define NF 4
#define AE 37

// ---------------- workspace layout (floats) ----------------
// attn   : [B*NAV]            @ 0        (576)
// dfa    : [B*NF]             @ 576      (64)
// vf_raw : [2][B][3][12]      @ 640      (1152)
// y1     : [2][B][64][269]    @ 1792     (550912)
// pano   : [B][360][1920]     @ 552704   (11059200)

__device__ __forceinline__ float rfl(float x) {
  return __int_as_float(__builtin_amdgcn_readfirstlane(__float_as_int(x)));
}

// ============ kernel 1: attn softmax + dynamic-filter MLP ============
__global__ __launch_bounds__(128) void k_head(
    const float* __restrict__ nnf, const float* __restrict__ ctx,
    const float* __restrict__ fc1w, const float* __restrict__ fc1b,
    const float* __restrict__ fc2w, const float* __restrict__ fc2b,
    float* __restrict__ attn, float* __restrict__ dfa) {
  int b = blockIdx.x;
  int t = threadIdx.x;  // 128 threads
  __shared__ float s_ctx[RH];
  __shared__ float s_v[NAV];
  __shared__ float s_hid[128];
  __shared__ float s_l[NF];
  __shared__ float s_inv[2];

  if (t < NAV) s_v[t] = nnf[b * NAV + t];
  for (int k = t; k < RH; k += 128) s_ctx[k] = ctx[b * RH + k];
  __syncthreads();

  if (t == 0) {
    float m = -1e30f;
    for (int i = 0; i < NAV; i++) m = fmaxf(m, s_v[i]);
    float s = 0.f;
    for (int i = 0; i < NAV; i++) { s_v[i] = expf(s_v[i] - m); s += s_v[i]; }
    s_inv[0] = 1.0f / s;
  }
  float acc = fc1b[t];
  const float* wr = fc1w + t * RH;
  for (int k = 0; k < RH; k++) acc += s_ctx[k] * wr[k];
  s_hid[t] = fmaxf(acc, 0.0f);
  __syncthreads();

  if (t < NAV) attn[b * NAV + t] = s_v[t] * s_inv[0];
  if (t < NF) {
    float a = fc2b[t];
    const float* w2 = fc2w + t * 128;
    for (int k = 0; k < 128; k++) a += s_hid[k] * w2[k];
    s_l[t] = a;
  }
  __syncthreads();
  if (t == 0) {
    float m = fmaxf(fmaxf(s_l[0], s_l[1]), fmaxf(s_l[2], s_l[3]));
    float s = 0.f;
    for (int f = 0; f < NF; f++) { s_l[f] = expf(s_l[f] - m); s += s_l[f]; }
    s_inv[1] = 1.0f / s;
  }
  __syncthreads();
  if (t < NF) dfa[b * NF + t] = s_l[t] * s_inv[1];
}

// ============ kernel 2: fused conv1 + attn-scale + dynamic conv -> pano ============
// TH=8 output rows x 160 cols of one (b,i) plane per block.
// Staged rows padded to 192 floats (768B = 6*128B: row-wrap keeps bank phase).
// pd stage: 246 items (6 row-pairs x 41 col-groups of 4), b128 window reads,
//           results held in regs across a barrier, then written into LDS
//           ALIASED over the dead raw/clip region (float4, 16B lane-stride).
// out stage: 256 items (8 rows x 32 groups of 5), scalar reads at stride-5
//           (gcd(5,32)=1 -> conflict-free).
// Weights hoisted to scalar regs via readfirstlane (block-uniform).
#define TH 8
#define LDW 192
__global__ __launch_bounds__(256) void k_conv(
    const float* __restrict__ draw, const float* __restrict__ dclip,
    const float* __restrict__ obj,
    const float* __restrict__ c1w, const float* __restrict__ c1b,
    const float* __restrict__ dynf,
    const float* __restrict__ attn, const float* __restrict__ dfa,
    float* __restrict__ pano) {
  __shared__ float s_A[2 * 16 * LDW];  // raw @0, clip @16*LDW (cols 0..171 used)
  __shared__ float s_w1[50];
  __shared__ float s_k[50];
  float* s_raw = s_A;
  float* s_clip = s_A + 16 * LDW;
  // aliases (used after pd compute; raw/clip dead then)
  float* s_pd = s_A;               // [12][LDW]
  float* s_po = s_A + 12 * LDW;    // [12][LDW]

  int t = threadIdx.x;
  int bz = blockIdx.z;
  int b = bz / NAV, i = bz % NAV;
  int y0 = blockIdx.y * TH;
  const size_t plane = (size_t)(b * NAV + i) * HIM * WIM;
  const float* rawp = draw + plane;
  const float* clipp = dclip + plane;
  const float* objp = obj + plane;
  float attn_bi = attn[b * NAV + i];

  if (t < 50) {
    s_w1[t] = c1w[i * 50 + t];
  } else if (t >= 64 && t < 114) {
    int j = t - 64;
    float a = 0.f;
    for (int f = 0; f < NF; f++) a += dfa[b * NF + f] * dynf[(f * NAV + i) * 50 + j];
    s_k[j] = a;
  }
  // stage raw/clip: 16 rows x 172 cols x 2 arrays = 5504 elems
  for (int idx = t; idx < 5504; idx += 256) {
    int a = idx >> 11 ? 1 : 0;          // idx/2752
    int rem = idx - a * 2752;
    int s = rem / 172, j = rem % 172;
    int gy = y0 - 4 + s, gx = j - 4;
    bool ok = (gy >= 0 && gy < HIM && gx >= 0 && gx < WIM);
    const float* src = a ? clipp : rawp;
    s_A[a * (16 * LDW) + s * LDW + j] = ok ? src[gy * WIM + gx] : 0.0f;
  }
  __syncthreads();

  // ---- pd stage: compute into registers ----
  float pdv[2][4];
  float pov[2][4];
  int rp = 0, g = 0;
  bool active = (t < 246);
  if (active) { rp = t / 41; g = t % 41; }
  {
    float w1s[50];
#pragma unroll
    for (int k = 0; k < 50; k++) w1s[k] = rfl(s_w1[k]);
    float bias = c1b[i];

    float acc[2][4];
#pragma unroll
    for (int o = 0; o < 2; o++)
#pragma unroll
      for (int co = 0; co < 4; co++) acc[o][co] = 0.f;

    if (active) {
      int cc0 = 4 * g;
#pragma unroll
      for (int rr = 0; rr < 6; rr++) {
        int s = 2 * rp + rr;
        float v[8], u[8];
        *(float4*)&v[0] = *(const float4*)&s_raw[s * LDW + cc0];
        *(float4*)&v[4] = *(const float4*)&s_raw[s * LDW + cc0 + 4];
        *(float4*)&u[0] = *(const float4*)&s_clip[s * LDW + cc0];
        *(float4*)&u[4] = *(const float4*)&s_clip[s * LDW + cc0 + 4];
#pragma unroll
        for (int o = 0; o < 2; o++) {
          int ky = rr - o;
          if (ky >= 0 && ky < 5) {
#pragma unroll
            for (int kx = 0; kx < 5; kx++) {
              float w0 = w1s[ky * 5 + kx], w1 = w1s[25 + ky * 5 + kx];
#pragma unroll
              for (int co = 0; co < 4; co++)
                acc[o][co] += v[co + kx] * w0 + u[co + kx] * w1;
            }
          }
        }
      }
      // finalize + load po
#pragma unroll
      for (int o = 0; o < 2; o++) {
        int r = 2 * rp + o;
        int y = y0 - 2 + r;
        bool yok = (y >= 0 && y < HIM);
#pragma unroll
        for (int co = 0; co < 4; co++) {
          int x = 4 * g + co - 2;
          bool ok = yok && (x >= 0 && x < WIM);
          pdv[o][co] = ok ? (bias + acc[o][co]) * attn_bi : 0.f;
          pov[o][co] = ok ? objp[y * WIM + x] * attn_bi : 0.f;
        }
      }
    }
  }
  __syncthreads();  // raw/clip now dead

  // write pd/po into aliased LDS (float4, 16B lane-stride: conflict-free)
  if (active) {
#pragma unroll
    for (int o = 0; o < 2; o++) {
      int r = 2 * rp + o;
      float4 p4 = {pdv[o][0], pdv[o][1], pdv[o][2], pdv[o][3]};
      float4 q4 = {pov[o][0], pov[o][1], pov[o][2], pov[o][3]};
      *(float4*)&s_pd[r * LDW + 4 * g] = p4;
      *(float4*)&s_po[r * LDW + 4 * g] = q4;
    }
  }
  __syncthreads();

  // ---- out stage: 8 rows x 32 groups of 5 = 256 items ----
  {
    float ks[50];
#pragma unroll
    for (int k = 0; k < 50; k++) ks[k] = rfl(s_k[k]);

    int dy = t >> 5, gg = t & 31;
    int x0 = 5 * gg;
    float a0 = 0.f, a1 = 0.f, a2 = 0.f, a3 = 0.f, a4 = 0.f;
#pragma unroll
    for (int ky = 0; ky < 5; ky++) {
      const float* pr = &s_pd[(dy + ky) * LDW + x0];
      const float* ob = &s_po[(dy + ky) * LDW + x0];
      float p[9], o9[9];
#pragma unroll
      for (int jj = 0; jj < 9; jj++) { p[jj] = pr[jj]; o9[jj] = ob[jj]; }
#pragma unroll
      for (int kx = 0; kx < 5; kx++) {
        float k1 = ks[ky * 5 + kx], k2 = ks[25 + ky * 5 + kx];
        a0 += p[kx] * k1 + o9[kx] * k2;
        a1 += p[kx + 1] * k1 + o9[kx + 1] * k2;
        a2 += p[kx + 2] * k1 + o9[kx + 2] * k2;
        a3 += p[kx + 3] * k1 + o9[kx + 3] * k2;
        a4 += p[kx + 4] * k1 + o9[kx + 4] * k2;
      }
    }
    int q = i / 12, cw = i % 12;
    float* outp = pano + (size_t)b * 360 * 1920 +
                  (size_t)((2 - q) * HIM + y0 + dy) * 1920 + cw * WIM + x0;
    outp[0] = a0; outp[1] = a1; outp[2] = a2; outp[3] = a3; outp[4] = a4;
  }
}

// ============ kernel 3: conv2_1, both roll paths, LDS row staging ============
__global__ __launch_bounds__(256) void k_c21(
    const float* __restrict__ pano, const float* __restrict__ w21,
    const float* __restrict__ b21, float* __restrict__ y1) {
  __shared__ float s_rows[5][1920];
  int t = threadIdx.x;
  int b = blockIdx.x, oy = blockIdx.y;
  const float* pp = pano + (size_t)b * 691200;
  for (int tt = t; tt < 2400; tt += 256) {
    int ky = tt / 480, g = tt % 480;
    int row = 5 * oy + 10 * ky;
    *(float4*)&s_rows[ky][4 * g] = *(const float4*)&pp[(size_t)row * 1920 + 4 * g];
  }
  float w[25];
#pragma unroll
  for (int k = 0; k < 25; k++) w[k] = w21[k];
  float bb = b21[0];
  __syncthreads();
  for (int tt = t; tt < 538; tt += 256) {
    int p = tt / 269, ox = tt % 269;
    int shift = p ? 1760 : 0;  // roll by +160 cols
    float acc = bb;
#pragma unroll
    for (int ky = 0; ky < 5; ky++)
#pragma unroll
      for (int kx = 0; kx < 5; kx++) {
        int X = 7 * ox + 10 * kx + shift;
        if (X >= 1920) X -= 1920;
        acc += w[ky * 5 + kx] * s_rows[ky][X];
      }
    y1[((size_t)(p * B + b) * 64 + oy) * 269 + ox] = acc;
  }
}

// ============ kernel 4: avgpool(3,3)/3 -> conv2_2 -> avgpool(3,9)/3 ============
__global__ __launch_bounds__(256) void k_tail(
    const float* __restrict__ y1, const float* __restrict__ w22,
    const float* __restrict__ b22, float* __restrict__ vf_raw) {
  __shared__ float s_y2[21][90];
  __shared__ float s_y3[10][44];
  int t = threadIdx.x;
  int pb = blockIdx.x;  // p*B+b
  const float* yp = y1 + (size_t)pb * 64 * 269;
  for (int idx = t; idx < 21 * 89; idx += 256) {
    int py = idx / 89, px = idx % 89;
    float s = 0.f;
    for (int dy = 0; dy < 3; dy++)
      for (int dx = 0; dx < 3; dx++)
        s += yp[(3 * py + dy) * 269 + 3 * px + dx];
    s_y2[py][px] = s * (1.0f / 9.0f);
  }
  __syncthreads();
  for (int idx = t; idx < 10 * 43; idx += 256) {
    int qy = idx / 43, qx = idx % 43;
    float a = b22[0];
#pragma unroll
    for (int ky = 0; ky < 3; ky++)
#pragma unroll
      for (int kx = 0; kx < 3; kx++)
        a += w22[ky * 3 + kx] * s_y2[2 * qy + ky][2 * qx + 2 * kx];
    s_y3[qy][qx] = a;
  }
  __syncthreads();
  if (t < 36) {
    int uy = t / 12, ux = t % 12;
    float s = 0.f;
    for (int dy = 0; dy < 3; dy++)
      for (int dx = 0; dx < 9; dx++)
        s += s_y3[3 * uy + dy][3 * ux + dx];
    vf_raw[pb * 36 + t] = s * (1.0f / 27.0f);
  }
}

// ============ kernel 5: combine paths, flip, softmax(T=10), nav_mask ============
__global__ __launch_bounds__(64) void k_vf(
    const float* __restrict__ vf_raw, const int* __restrict__ nav_idx,
    float* __restrict__ out_vf, float* __restrict__ out_mask) {
  int b = blockIdx.x;
  int t = threadIdx.x;  // 64
  __shared__ float s_v[36];
  __shared__ float s_inv;
  if (t < 36) {
    int u = t / 12, x = t % 12;
    float v1 = vf_raw[(0 * B + b) * 36 + (2 - u) * 12 + x];
    float v2 = vf_raw[(1 * B + b) * 36 + (2 - u) * 12 + (x + 1) % 12];
    s_v[t] = 0.5f * (v1 + v2) * 0.1f;  // /TEMP
  }
  __syncthreads();
  if (t == 0) {
    float m = -1e30f;
    for (int i = 0; i < 36; i++) m = fmaxf(m, s_v[i]);
    float s = 0.f;
    for (int i = 0; i < 36; i++) { s_v[i] = expf(s_v[i] - m); s += s_v[i]; }
    s_inv = 1.0f / s;
  }
  __syncthreads();
  if (t < 36) {
    out_vf[b * 36 + t] = s_v[t] * s_inv;
    float m = 0.f;
    for (int e = 0; e < 8; e++)
      if (nav_idx[b * 8 + e] == t) m = 1.0f;
    out_mask[b * 36 + t] = m;
  }
}

// ============ kernel 6: LSTM cell ============
__global__ __launch_bounds__(256) void k_lstm(
    const float* __restrict__ ctx, const float* __restrict__ vf,
    const float* __restrict__ dfa, const float* __restrict__ pre,
    const float* __restrict__ h0, const float* __restrict__ c0,
    const float* __restrict__ wih, const float* __restrict__ whh,
    const float* __restrict__ bih, const float* __restrict__ bhh,
    float* __restrict__ h1, float* __restrict__ c1) {
  __shared__ float s_cat[B][593];
  __shared__ float s_g[32][16];
  int t = threadIdx.x;
  int u0 = blockIdx.x * 8;
  for (int idx = t; idx < B * 589; idx += 256) {
    int b = idx / 589, k = idx % 589;
    float v;
    if (k < 512) v = ctx[b * 512 + k];
    else if (k < 548) v = vf[b * 36 + (k - 512)];
    else if (k < 552) v = dfa[b * 4 + (k - 548)];
    else v = pre[b * 37 + (k - 552)];
    s_cat[b][k] = v;
  }
  __syncthreads();
  int b = t & 15;
  int s0 = t >> 4;
  for (int rep = 0; rep < 2; rep++) {
    int slot = s0 + rep * 16;
    int gate = slot >> 3, du = slot & 7;
    int j = gate * 512 + u0 + du;
    float acc = bih[j] + bhh[j];
    const float* wi = wih + (size_t)j * 589;
    for (int k = 0; k < 589; k++) acc += s_cat[b][k] * wi[k];
    const float* wh = whh + (size_t)j * 512;
    const float* hb = h0 + b * 512;
    for (int k = 0; k < 512; k++) acc += hb[k] * wh[k];
    s_g[slot][b] = acc;
  }
  __syncthreads();
  if (t < 128) {
    int bb = t & 15, du = t >> 4;
    float gi = s_g[0 + du][bb], gf = s_g[8 + du][bb];
    float gg = s_g[16 + du][bb], go = s_g[24 + du][bb];
    int u = u0 + du;
    float c_old = c0[bb * 512 + u];
    float si = 1.0f / (1.0f + expf(-gi));
    float sf = 1.0f / (1.0f + expf(-gf));
    float so = 1.0f / (1.0f + expf(-go));
    float cn = sf * c_old + si * tanhf(gg);
    h1[bb * 512 + u] = so * tanhf(cn);
    c1[bb * 512 + u] = cn;
  }
}

extern "C" void kernel_launch(void* const* d_in, const int* in_sizes, int n_in,
                              void* d_out, int out_size, void* d_ws, size_t ws_size,
                              hipStream_t stream) {
  const float* depth_raw  = (const float*)d_in[0];
  const float* depth_clip = (const float*)d_in[1];
  const float* obj_feat   = (const float*)d_in[2];
  const float* nnf        = (const float*)d_in[3];
  const float* pre        = (const float*)d_in[4];
  const float* h0         = (const float*)d_in[5];
  const float* c0         = (const float*)d_in[6];
  const float* ctx        = (const float*)d_in[7];
  const int*   nav_idx    = (const int*)d_in[8];
  const float* c1w        = (const float*)d_in[9];
  const float* c1b        = (const float*)d_in[10];
  const float* fc1w       = (const float*)d_in[11];
  const float* fc1b       = (const float*)d_in[12];
  const float* fc2w       = (const float*)d_in[13];
  const float* fc2b       = (const float*)d_in[14];
  const float* dynf       = (const float*)d_in[15];
  const float* w21        = (const float*)d_in[16];
  const float* b21        = (const float*)d_in[17];
  const float* w22        = (const float*)d_in[18];
  const float* b22        = (const float*)d_in[19];
  const float* wih        = (const float*)d_in[20];
  const float* whh        = (const float*)d_in[21];
  const float* bih        = (const float*)d_in[22];
  const float* bhh        = (const float*)d_in[23];

  float* ws = (float*)d_ws;
  float* attn   = ws;
  float* dfa    = ws + 576;
  float* vf_raw = ws + 640;
  float* y1     = ws + 1792;
  float* pano   = ws + 552704;

  float* out = (float*)d_out;
  float* out_h1   = out;
  float* out_c1   = out + 8192;
  float* out_vf   = out + 16384;
  float* out_mask = out + 16960;

  k_head<<<B, 128, 0, stream>>>(nnf, ctx, fc1w, fc1b, fc2w, fc2b, attn, dfa);
  k_conv<<<dim3(1, 15, B * NAV), 256, 0, stream>>>(depth_raw, depth_clip, obj_feat,
                                                   c1w, c1b, dynf, attn, dfa, pano);
  k_c21<<<dim3(B, 64), 256, 0, stream>>>(pano, w21, b21, y1);
  k_tail<<<2 * B, 256, 0, stream>>>(y1, w22, b22, vf_raw);
  k_vf<<<B, 64, 0, stream>>>(vf_raw, nav_idx, out_vf, out_mask);
  k_lstm<<<64, 256, 0, stream>>>(ctx, out_vf, dfa, pre, h0, c0,
                                 wih, whh, bih, bhh, out_h1, out_c1);
}

// Round 5
// 152.180 us; speedup vs baseline: 2.3526x; 1.4812x over previous
//
#include <hip/hip_runtime.h>
#include <math.h>

#define B 16
#define NAV 36
#define HIM 120
#define WIM 160
#define RH 512
#define NF 4
#define AE 37

// ---------------- workspace layout (floats) ----------------
// attn   : [B*NAV]            @ 0        (576)
// dfa    : [B*NF]             @ 576      (64)
// vf_raw : [2][B][3][12]      @ 640      (1152)
// y1     : [2][B][64][269]    @ 1792     (550912)
// pano   : [B][360][1920]     @ 552704   (11059200)

__device__ __forceinline__ float rfl(float x) {
  return __int_as_float(__builtin_amdgcn_readfirstlane(__float_as_int(x)));
}

// ============ kernel 1: attn softmax + dynamic-filter MLP ============
__global__ __launch_bounds__(128) void k_head(
    const float* __restrict__ nnf, const float* __restrict__ ctx,
    const float* __restrict__ fc1w, const float* __restrict__ fc1b,
    const float* __restrict__ fc2w, const float* __restrict__ fc2b,
    float* __restrict__ attn, float* __restrict__ dfa) {
  int b = blockIdx.x;
  int t = threadIdx.x;  // 128 threads
  __shared__ float s_ctx[RH];
  __shared__ float s_v[NAV];
  __shared__ float s_hid[128];
  __shared__ float s_l[NF];
  __shared__ float s_inv[2];

  if (t < NAV) s_v[t] = nnf[b * NAV + t];
  for (int k = t; k < RH; k += 128) s_ctx[k] = ctx[b * RH + k];
  __syncthreads();

  if (t == 0) {
    float m = -1e30f;
    for (int i = 0; i < NAV; i++) m = fmaxf(m, s_v[i]);
    float s = 0.f;
    for (int i = 0; i < NAV; i++) { s_v[i] = expf(s_v[i] - m); s += s_v[i]; }
    s_inv[0] = 1.0f / s;
  }
  float acc = fc1b[t];
  const float* wr = fc1w + t * RH;
  for (int k = 0; k < RH; k++) acc += s_ctx[k] * wr[k];
  s_hid[t] = fmaxf(acc, 0.0f);
  __syncthreads();

  if (t < NAV) attn[b * NAV + t] = s_v[t] * s_inv[0];
  if (t < NF) {
    float a = fc2b[t];
    const float* w2 = fc2w + t * 128;
    for (int k = 0; k < 128; k++) a += s_hid[k] * w2[k];
    s_l[t] = a;
  }
  __syncthreads();
  if (t == 0) {
    float m = fmaxf(fmaxf(s_l[0], s_l[1]), fmaxf(s_l[2], s_l[3]));
    float s = 0.f;
    for (int f = 0; f < NF; f++) { s_l[f] = expf(s_l[f] - m); s += s_l[f]; }
    s_inv[1] = 1.0f / s;
  }
  __syncthreads();
  if (t < NF) dfa[b * NF + t] = s_l[t] * s_inv[1];
}

// ============ kernel 2: fused conv1 + attn-scale + dynamic conv -> pano ============
// TH=8 output rows x 160 cols of one (b,i) plane per block.
// LDS rows 192 floats (768B = 0 mod 128B -> all rows bank-phase 0).
// Phase 0: zero halo cols (1 write/thread), stage interior as float4 with
//          shift/mask addressing only (no div, no per-element bounds).
// Phase 2: issue obj float4 loads EARLY (latency hides under pd FMAs),
//          compute pd in regs (246 threads, b128 window reads, 400 FMA).
// Phase 4: write pd + attn*obj into LDS aliased over dead raw/clip.
// Phase 6: out stage, 256 items (8 rows x 32 groups of 5), stride-5 reads.
#define TH 8
#define LDW 192
__global__ __launch_bounds__(256) void k_conv(
    const float* __restrict__ draw, const float* __restrict__ dclip,
    const float* __restrict__ obj,
    const float* __restrict__ c1w, const float* __restrict__ c1b,
    const float* __restrict__ dynf,
    const float* __restrict__ attn, const float* __restrict__ dfa,
    float* __restrict__ pano) {
  __shared__ __align__(16) float s_A[32 * LDW];  // raw[16][LDW] @0, clip[16][LDW] @16*LDW
  __shared__ float s_w1[50];
  __shared__ float s_k[50];
  float* s_raw = s_A;                // col j = gx+4 (gx -4..163 -> j 0..167)
  float* s_clip = s_A + 16 * LDW;
  // aliases (valid after raw/clip are dead):
  float* s_pd = s_A;                 // [12][LDW], col c = x+2
  float* s_po = s_A + 12 * LDW;      // [12][LDW], col j = x+4 (same layout as raw)

  int t = threadIdx.x;
  int bz = blockIdx.z;
  int b = bz / NAV, i = bz % NAV;
  int y0 = blockIdx.y * TH;
  const size_t plane = (size_t)(b * NAV + i) * HIM * WIM;
  const float* rawp = draw + plane;
  const float* clipp = dclip + plane;
  const float* objp = obj + plane;
  float attn_bi = attn[b * NAV + i];
  float bias = c1b[i];

  // phase 0a: weights
  if (t < 50) {
    s_w1[t] = c1w[i * 50 + t];
  } else if (t >= 64 && t < 114) {
    int j = t - 64;
    float a = 0.f;
    for (int f = 0; f < NF; f++) a += dfa[b * NF + f] * dynf[(f * NAV + i) * 50 + j];
    s_k[j] = a;
  }
  // phase 0b: zero halo cols (16 rows x 8 cols x 2 arrays = 256 writes)
  {
    int half = t >> 7;            // 0=raw, 1=clip
    int r = (t >> 3) & 15;
    int hc = t & 7;
    int col = hc < 4 ? hc : 160 + hc;  // 0..3, 164..167
    s_A[half * (16 * LDW) + r * LDW + col] = 0.f;
  }
  // phase 0c: interior staging, pure float4 (thread = (row, lane16))
  {
    int r = t >> 4;               // 0..15
    int lane16 = t & 15;
    int gy = y0 - 4 + r;
    bool yok = (gy >= 0 && gy < HIM);
    const float* gr = rawp + gy * WIM;
    const float* gc = clipp + gy * WIM;
#pragma unroll
    for (int jj = 0; jj < 3; jj++) {
      int g = lane16 + 16 * jj;   // float4 group, 0..47; valid < 40
      bool act = (g < 40);
      float4 vr = {0.f, 0.f, 0.f, 0.f}, vc = {0.f, 0.f, 0.f, 0.f};
      if (act && yok) {
        vr = *(const float4*)(gr + 4 * g);
        vc = *(const float4*)(gc + 4 * g);
      }
      if (act) {
        *(float4*)&s_raw[r * LDW + 4 + 4 * g] = vr;
        *(float4*)&s_clip[r * LDW + 4 + 4 * g] = vc;
      }
    }
  }
  __syncthreads();

  // phase 2a: issue obj loads early (consumed after next barrier)
  float4 pol[2];
  int por[2], pog[2];
  bool poa[2];
#pragma unroll
  for (int jj = 0; jj < 2; jj++) {
    int idx = t + 256 * jj;       // [0,512); valid < 480 = 12 rows * 40 groups
    bool act = (idx < 480);
    int r2 = idx / 40, g = idx - 40 * r2;
    int gy = y0 - 2 + r2;
    float4 v = {0.f, 0.f, 0.f, 0.f};
    if (act && gy >= 0 && gy < HIM) v = *(const float4*)(objp + gy * WIM + 4 * g);
    pol[jj] = v; por[jj] = r2; pog[jj] = g; poa[jj] = act;
  }

  // phase 2b: pd compute into registers (246 threads: 6 row-pairs x 41 groups)
  float pdv[2][4];
  int rp = 0, gq = 0;
  bool pact = (t < 246);
  if (pact) { rp = t / 41; gq = t - 41 * rp; }
  {
    float w1s[50];
#pragma unroll
    for (int k = 0; k < 50; k++) w1s[k] = rfl(s_w1[k]);

    float acc[2][4];
#pragma unroll
    for (int o = 0; o < 2; o++)
#pragma unroll
      for (int co = 0; co < 4; co++) acc[o][co] = 0.f;

    if (pact) {
      int cc0 = 4 * gq;
#pragma unroll
      for (int rr = 0; rr < 6; rr++) {
        int s = 2 * rp + rr;
        float v[8], u[8];
        *(float4*)&v[0] = *(const float4*)&s_raw[s * LDW + cc0];
        *(float4*)&v[4] = *(const float4*)&s_raw[s * LDW + cc0 + 4];
        *(float4*)&u[0] = *(const float4*)&s_clip[s * LDW + cc0];
        *(float4*)&u[4] = *(const float4*)&s_clip[s * LDW + cc0 + 4];
#pragma unroll
        for (int o = 0; o < 2; o++) {
          int ky = rr - o;
          if (ky >= 0 && ky < 5) {
#pragma unroll
            for (int kx = 0; kx < 5; kx++) {
              float w0 = w1s[ky * 5 + kx], w1 = w1s[25 + ky * 5 + kx];
#pragma unroll
              for (int co = 0; co < 4; co++)
                acc[o][co] += v[co + kx] * w0 + u[co + kx] * w1;
            }
          }
        }
      }
#pragma unroll
      for (int o = 0; o < 2; o++) {
        int r = 2 * rp + o;
        int y = y0 - 2 + r;
        bool yok = (y >= 0 && y < HIM);
#pragma unroll
        for (int co = 0; co < 4; co++) {
          int x = 4 * gq + co - 2;
          bool ok = yok && (x >= 0) && (x < WIM);
          pdv[o][co] = ok ? (bias + acc[o][co]) * attn_bi : 0.f;
        }
      }
    }
  }
  __syncthreads();  // raw/clip now dead

  // phase 4: write pd + scaled po into aliased LDS (float4, 16B lane-stride)
  if (pact) {
#pragma unroll
    for (int o = 0; o < 2; o++) {
      float4 p4 = {pdv[o][0], pdv[o][1], pdv[o][2], pdv[o][3]};
      *(float4*)&s_pd[(2 * rp + o) * LDW + 4 * gq] = p4;
    }
  }
#pragma unroll
  for (int jj = 0; jj < 2; jj++) {
    if (poa[jj]) {
      float4 v = pol[jj];
      v.x *= attn_bi; v.y *= attn_bi; v.z *= attn_bi; v.w *= attn_bi;
      *(float4*)&s_po[por[jj] * LDW + 4 + 4 * pog[jj]] = v;
    }
  }
  __syncthreads();

  // phase 6: out stage, 8 rows x 32 groups of 5 = 256 items
  {
    float ks[50];
#pragma unroll
    for (int k = 0; k < 50; k++) ks[k] = rfl(s_k[k]);

    int dy = t >> 5, gg = t & 31;
    int x0 = 5 * gg;
    float a0 = 0.f, a1 = 0.f, a2 = 0.f, a3 = 0.f, a4 = 0.f;
#pragma unroll
    for (int ky = 0; ky < 5; ky++) {
      const float* pr = &s_pd[(dy + ky) * LDW + x0];       // pd col = x0 + (kx+j)
      const float* ob = &s_po[(dy + ky) * LDW + x0 + 2];   // po col = x0+2 + (kx+j)
      float p[9], o9[9];
#pragma unroll
      for (int jj = 0; jj < 9; jj++) { p[jj] = pr[jj]; o9[jj] = ob[jj]; }
#pragma unroll
      for (int kx = 0; kx < 5; kx++) {
        float k1 = ks[ky * 5 + kx], k2 = ks[25 + ky * 5 + kx];
        a0 += p[kx] * k1 + o9[kx] * k2;
        a1 += p[kx + 1] * k1 + o9[kx + 1] * k2;
        a2 += p[kx + 2] * k1 + o9[kx + 2] * k2;
        a3 += p[kx + 3] * k1 + o9[kx + 3] * k2;
        a4 += p[kx + 4] * k1 + o9[kx + 4] * k2;
      }
    }
    int q = i / 12, cw = i % 12;
    float* outp = pano + (size_t)b * 360 * 1920 +
                  (size_t)((2 - q) * HIM + y0 + dy) * 1920 + cw * WIM + x0;
    outp[0] = a0; outp[1] = a1; outp[2] = a2; outp[3] = a3; outp[4] = a4;
  }
}

// ============ kernel 3: conv2_1, both roll paths, LDS row staging ============
__global__ __launch_bounds__(256) void k_c21(
    const float* __restrict__ pano, const float* __restrict__ w21,
    const float* __restrict__ b21, float* __restrict__ y1) {
  __shared__ float s_rows[5][1920];
  int t = threadIdx.x;
  int b = blockIdx.x, oy = blockIdx.y;
  const float* pp = pano + (size_t)b * 691200;
  for (int tt = t; tt < 2400; tt += 256) {
    int ky = tt / 480, g = tt % 480;
    int row = 5 * oy + 10 * ky;
    *(float4*)&s_rows[ky][4 * g] = *(const float4*)&pp[(size_t)row * 1920 + 4 * g];
  }
  float w[25];
#pragma unroll
  for (int k = 0; k < 25; k++) w[k] = w21[k];
  float bb = b21[0];
  __syncthreads();
  for (int tt = t; tt < 538; tt += 256) {
    int p = tt / 269, ox = tt % 269;
    int shift = p ? 1760 : 0;  // roll by +160 cols
    float acc = bb;
#pragma unroll
    for (int ky = 0; ky < 5; ky++)
#pragma unroll
      for (int kx = 0; kx < 5; kx++) {
        int X = 7 * ox + 10 * kx + shift;
        if (X >= 1920) X -= 1920;
        acc += w[ky * 5 + kx] * s_rows[ky][X];
      }
    y1[((size_t)(p * B + b) * 64 + oy) * 269 + ox] = acc;
  }
}

// ============ kernel 4: avgpool(3,3)/3 -> conv2_2 -> avgpool(3,9)/3 ============
__global__ __launch_bounds__(256) void k_tail(
    const float* __restrict__ y1, const float* __restrict__ w22,
    const float* __restrict__ b22, float* __restrict__ vf_raw) {
  __shared__ float s_y2[21][90];
  __shared__ float s_y3[10][44];
  int t = threadIdx.x;
  int pb = blockIdx.x;  // p*B+b
  const float* yp = y1 + (size_t)pb * 64 * 269;
  for (int idx = t; idx < 21 * 89; idx += 256) {
    int py = idx / 89, px = idx % 89;
    float s = 0.f;
    for (int dy = 0; dy < 3; dy++)
      for (int dx = 0; dx < 3; dx++)
        s += yp[(3 * py + dy) * 269 + 3 * px + dx];
    s_y2[py][px] = s * (1.0f / 9.0f);
  }
  __syncthreads();
  for (int idx = t; idx < 10 * 43; idx += 256) {
    int qy = idx / 43, qx = idx % 43;
    float a = b22[0];
#pragma unroll
    for (int ky = 0; ky < 3; ky++)
#pragma unroll
      for (int kx = 0; kx < 3; kx++)
        a += w22[ky * 3 + kx] * s_y2[2 * qy + ky][2 * qx + 2 * kx];
    s_y3[qy][qx] = a;
  }
  __syncthreads();
  if (t < 36) {
    int uy = t / 12, ux = t % 12;
    float s = 0.f;
    for (int dy = 0; dy < 3; dy++)
      for (int dx = 0; dx < 9; dx++)
        s += s_y3[3 * uy + dy][3 * ux + dx];
    vf_raw[pb * 36 + t] = s * (1.0f / 27.0f);
  }
}

// ============ kernel 5: combine paths, flip, softmax(T=10), nav_mask ============
__global__ __launch_bounds__(64) void k_vf(
    const float* __restrict__ vf_raw, const int* __restrict__ nav_idx,
    float* __restrict__ out_vf, float* __restrict__ out_mask) {
  int b = blockIdx.x;
  int t = threadIdx.x;  // 64
  __shared__ float s_v[36];
  __shared__ float s_inv;
  if (t < 36) {
    int u = t / 12, x = t % 12;
    float v1 = vf_raw[(0 * B + b) * 36 + (2 - u) * 12 + x];
    float v2 = vf_raw[(1 * B + b) * 36 + (2 - u) * 12 + (x + 1) % 12];
    s_v[t] = 0.5f * (v1 + v2) * 0.1f;  // /TEMP
  }
  __syncthreads();
  if (t == 0) {
    float m = -1e30f;
    for (int i = 0; i < 36; i++) m = fmaxf(m, s_v[i]);
    float s = 0.f;
    for (int i = 0; i < 36; i++) { s_v[i] = expf(s_v[i] - m); s += s_v[i]; }
    s_inv = 1.0f / s;
  }
  __syncthreads();
  if (t < 36) {
    out_vf[b * 36 + t] = s_v[t] * s_inv;
    float m = 0.f;
    for (int e = 0; e < 8; e++)
      if (nav_idx[b * 8 + e] == t) m = 1.0f;
    out_mask[b * 36 + t] = m;
  }
}

// ============ kernel 6: LSTM cell (128 blocks, 1 dot per thread) ============
__global__ __launch_bounds__(256) void k_lstm(
    const float* __restrict__ ctx, const float* __restrict__ vf,
    const float* __restrict__ dfa, const float* __restrict__ pre,
    const float* __restrict__ h0, const float* __restrict__ c0,
    const float* __restrict__ wih, const float* __restrict__ whh,
    const float* __restrict__ bih, const float* __restrict__ bhh,
    float* __restrict__ h1, float* __restrict__ c1) {
  __shared__ float s_cat[B][593];
  __shared__ float s_g[16][16];
  int t = threadIdx.x;
  int u0 = blockIdx.x * 4;
  for (int idx = t; idx < B * 589; idx += 256) {
    int b = idx / 589, k = idx % 589;
    float v;
    if (k < 512) v = ctx[b * 512 + k];
    else if (k < 548) v = vf[b * 36 + (k - 512)];
    else if (k < 552) v = dfa[b * 4 + (k - 548)];
    else v = pre[b * 37 + (k - 552)];
    s_cat[b][k] = v;
  }
  __syncthreads();
  int b = t & 15;
  int slot = t >> 4;               // gate*4 + du
  int gate = slot >> 2, du = slot & 3;
  int j = gate * 512 + u0 + du;
  float acc = bih[j] + bhh[j];
  const float* wi = wih + (size_t)j * 589;
  for (int k = 0; k < 589; k++) acc += s_cat[b][k] * wi[k];
  const float* wh = whh + (size_t)j * 512;
  const float* hb = h0 + b * 512;
  for (int k = 0; k < 512; k++) acc += hb[k] * wh[k];
  s_g[slot][b] = acc;
  __syncthreads();
  if (t < 64) {
    int bb = t & 15, du2 = t >> 4;  // 0..3
    float gi = s_g[du2][bb], gf = s_g[4 + du2][bb];
    float gg = s_g[8 + du2][bb], go = s_g[12 + du2][bb];
    int u = u0 + du2;
    float c_old = c0[bb * 512 + u];
    float si = 1.0f / (1.0f + expf(-gi));
    float sf = 1.0f / (1.0f + expf(-gf));
    float so = 1.0f / (1.0f + expf(-go));
    float cn = sf * c_old + si * tanhf(gg);
    h1[bb * 512 + u] = so * tanhf(cn);
    c1[bb * 512 + u] = cn;
  }
}

extern "C" void kernel_launch(void* const* d_in, const int* in_sizes, int n_in,
                              void* d_out, int out_size, void* d_ws, size_t ws_size,
                              hipStream_t stream) {
  const float* depth_raw  = (const float*)d_in[0];
  const float* depth_clip = (const float*)d_in[1];
  const float* obj_feat   = (const float*)d_in[2];
  const float* nnf        = (const float*)d_in[3];
  const float* pre        = (const float*)d_in[4];
  const float* h0         = (const float*)d_in[5];
  const float* c0         = (const float*)d_in[6];
  const float* ctx        = (const float*)d_in[7];
  const int*   nav_idx    = (const int*)d_in[8];
  const float* c1w        = (const float*)d_in[9];
  const float* c1b        = (const float*)d_in[10];
  const float* fc1w       = (const float*)d_in[11];
  const float* fc1b       = (const float*)d_in[12];
  const float* fc2w       = (const float*)d_in[13];
  const float* fc2b       = (const float*)d_in[14];
  const float* dynf       = (const float*)d_in[15];
  const float* w21        = (const float*)d_in[16];
  const float* b21        = (const float*)d_in[17];
  const float* w22        = (const float*)d_in[18];
  const float* b22        = (const float*)d_in[19];
  const float* wih        = (const float*)d_in[20];
  const float* whh        = (const float*)d_in[21];
  const float* bih        = (const float*)d_in[22];
  const float* bhh        = (const float*)d_in[23];

  float* ws = (float*)d_ws;
  float* attn   = ws;
  float* dfa    = ws + 576;
  float* vf_raw = ws + 640;
  float* y1     = ws + 1792;
  float* pano   = ws + 552704;

  float* out = (float*)d_out;
  float* out_h1   = out;
  float* out_c1   = out + 8192;
  float* out_vf   = out + 16384;
  float* out_mask = out + 16960;

  k_head<<<B, 128, 0, stream>>>(nnf, ctx, fc1w, fc1b, fc2w, fc2b, attn, dfa);
  k_conv<<<dim3(1, 15, B * NAV), 256, 0, stream>>>(depth_raw, depth_clip, obj_feat,
                                                   c1w, c1b, dynf, attn, dfa, pano);
  k_c21<<<dim3(B, 64), 256, 0, stream>>>(pano, w21, b21, y1);
  k_tail<<<2 * B, 256, 0, stream>>>(y1, w22, b22, vf_raw);
  k_vf<<<B, 64, 0, stream>>>(vf_raw, nav_idx, out_vf, out_mask);
  k_lstm<<<128, 256, 0, stream>>>(ctx, out_vf, dfa, pre, h0, c0,
                                  wih, whh, bih, bhh, out_h1, out_c1);
}